// Round 1
// baseline (1461.039 us; speedup 1.0000x reference)
//
#include <hip/hip_runtime.h>
#include <math.h>

// Shapes fixed by the problem: B=2, S=2048, D=1024, H=16, hd=64.
// Outputs: out (B,S,D)=4194304 floats, then qk (B,H,S,S)=134217728 floats.
//
// Key reference semantics:
//  - masking is MULTIPLICATIVE: masked logits are 0 (not -inf); softmax rows
//    include exp(0) for all k>q, and attn includes e^{-m}/Z * sum_{k>q} v.
//  - k projection has NO bias; token_ids = k[...,0] AFTER RoPE, compared ==0.
//  - scale^2 = hd^-0.5 = 1/8, folded into Q staging.

#define SEQ 2048
#define DIM 1024
#define NHEAD 16
#define HD 64
#define NT 32  // SEQ/64

// ---------------- K0: RoPE tables ----------------
static __global__ __launch_bounds__(256) void rope_tables_k(
    float* __restrict__ cosT, float* __restrict__ sinT)
{
    int idx = blockIdx.x * 256 + threadIdx.x;   // 2048*32 = 65536
    int s = idx >> 5, i = idx & 31;
    float inv = powf(10000.0f, -(float)(2 * i) / 64.0f);
    float ang = (float)s * inv;
    cosT[idx] = cosf(ang);
    sinT[idx] = sinf(ang);
}

// ---------------- K1/K3: C = A @ W^T (+bias), tiled 64x64x16 ----------------
// mode 0: Q (bias, RoPE, head layout)  1: K (no bias, RoPE, head layout)
// mode 2: V (bias, head layout)        3: out = AT @ Wo^T + bo (row-major)
static __global__ __launch_bounds__(256) void gemm_nt_k(
    const float* __restrict__ x, const float* __restrict__ ATin,
    const float* __restrict__ Wq, const float* __restrict__ bq,
    const float* __restrict__ Wk,
    const float* __restrict__ Wv, const float* __restrict__ bv,
    const float* __restrict__ Wo, const float* __restrict__ bo,
    const float* __restrict__ cosT, const float* __restrict__ sinT,
    float* __restrict__ Qh, float* __restrict__ Kh, float* __restrict__ Vh,
    float* __restrict__ outp, int mode_base)
{
    int mode = mode_base + blockIdx.z;
    const float* A = (mode == 3) ? ATin : x;
    const float* W;
    const float* bias;
    if (mode == 0)      { W = Wq; bias = bq; }
    else if (mode == 1) { W = Wk; bias = nullptr; }
    else if (mode == 2) { W = Wv; bias = bv; }
    else                { W = Wo; bias = bo; }

    __shared__ float As[16][68];  // transposed: As[k][m], pad 68 -> 16B-aligned rows
    __shared__ float Bs[16][68];  // transposed: Bs[k][n]

    int tid = threadIdx.x;
    int tx = tid & 15, ty = tid >> 4;
    int m0 = blockIdx.y * 64, n0 = blockIdx.x * 64;
    int lrow = tid >> 2, lk = (tid & 3) * 4;

    const float* ag = A + (size_t)(m0 + lrow) * DIM + lk;
    const float* wg = W + (size_t)(n0 + lrow) * DIM + lk;

    float c[4][4] = {};

    for (int k0 = 0; k0 < DIM; k0 += 16) {
        float4 av  = *(const float4*)(ag + k0);
        float4 bv4 = *(const float4*)(wg + k0);
        __syncthreads();
        As[lk + 0][lrow] = av.x;  As[lk + 1][lrow] = av.y;
        As[lk + 2][lrow] = av.z;  As[lk + 3][lrow] = av.w;
        Bs[lk + 0][lrow] = bv4.x; Bs[lk + 1][lrow] = bv4.y;
        Bs[lk + 2][lrow] = bv4.z; Bs[lk + 3][lrow] = bv4.w;
        __syncthreads();
#pragma unroll
        for (int kk = 0; kk < 16; ++kk) {
            float4 a4 = *(const float4*)&As[kk][ty * 4];
            float4 b4 = *(const float4*)&Bs[kk][tx * 4];
            float aa[4] = {a4.x, a4.y, a4.z, a4.w};
            float bb[4] = {b4.x, b4.y, b4.z, b4.w};
#pragma unroll
            for (int i = 0; i < 4; ++i)
#pragma unroll
                for (int j = 0; j < 4; ++j)
                    c[i][j] = fmaf(aa[i], bb[j], c[i][j]);
        }
    }

    if (bias) {
        float bb[4];
#pragma unroll
        for (int j = 0; j < 4; ++j) bb[j] = bias[n0 + tx * 4 + j];
#pragma unroll
        for (int i = 0; i < 4; ++i)
#pragma unroll
            for (int j = 0; j < 4; ++j) c[i][j] += bb[j];
    }

    if (mode == 3) {
#pragma unroll
        for (int i = 0; i < 4; ++i) {
            int m = m0 + ty * 4 + i;
            float4 o = {c[i][0], c[i][1], c[i][2], c[i][3]};
            *(float4*)(outp + (size_t)m * DIM + n0 + tx * 4) = o;
        }
        return;
    }

    float* Out = (mode == 0) ? Qh : (mode == 1) ? Kh : Vh;
    int h = n0 >> 6;     // n0 is a multiple of 64
    int d = tx * 4;      // even -> RoPE pairs (d,d+1),(d+2,d+3)
#pragma unroll
    for (int i = 0; i < 4; ++i) {
        int m = m0 + ty * 4 + i;
        int s = m & (SEQ - 1), b = m >> 11;
        float4 o;
        if (mode <= 1) {
            int p0 = d >> 1;
            float c0 = cosT[s * 32 + p0],     s0 = sinT[s * 32 + p0];
            float c1 = cosT[s * 32 + p0 + 1], s1 = sinT[s * 32 + p0 + 1];
            o.x = c[i][0] * c0 - c[i][1] * s0;
            o.y = c[i][0] * s0 + c[i][1] * c0;
            o.z = c[i][2] * c1 - c[i][3] * s1;
            o.w = c[i][2] * s1 + c[i][3] * c1;
        } else {
            o = make_float4(c[i][0], c[i][1], c[i][2], c[i][3]);
        }
        *(float4*)(Out + ((size_t)((b * NHEAD + h) * SEQ + s)) * HD + d) = o;
    }
}

// ---------------- K1b: per-(b,h) suffix sums of V over 64-row tiles ----------------
static __global__ __launch_bounds__(256) void vsuffix_k(
    const float* __restrict__ Vh, float* __restrict__ suf)
{
    __shared__ float ts[NT][HD];
    int bh = blockIdx.x;
    int tg = threadIdx.x >> 6, d = threadIdx.x & 63;
    const float* Vp = Vh + (size_t)bh * SEQ * HD + d;
    for (int t = tg; t < NT; t += 4) {
        float s = 0.f;
#pragma unroll
        for (int c = 0; c < 64; ++c) s += Vp[(size_t)(t * 64 + c) * HD];
        ts[t][d] = s;
    }
    __syncthreads();
    if (tg == 0) {
        float acc = 0.f;
        suf[((size_t)bh * (NT + 1) + NT) * HD + d] = 0.f;
        for (int t = NT - 1; t >= 0; --t) {
            acc += ts[t][d];
            suf[((size_t)bh * (NT + 1) + t) * HD + d] = acc;
        }
    }
}

// ---------------- K2: fused attention (writes qk + attn) ----------------
static __global__ __launch_bounds__(256) void attn_k(
    const float* __restrict__ Qh, const float* __restrict__ Kh,
    const float* __restrict__ Vh, const float* __restrict__ suf,
    const float* __restrict__ factorp,
    float* __restrict__ qkout, float* __restrict__ AT)
{
    __shared__ float Qt[64][68];   // Q^T * scale^2: Qt[d][qr]
    __shared__ float KP[64][68];   // K^T during scores, then P^T during PV
    __shared__ float Vs[64][68];   // V row-major

    int qt = blockIdx.x, bh = blockIdx.y;
    int b = bh >> 4, h = bh & 15;
    int tid = threadIdx.x;
    int tx = tid & 15, ty = tid >> 4;
    int q0 = qt * 64;

    float fac = *factorp;
    float sp = log1pf(expf(fac));
    float zf = fminf(fmaxf(sp, 1e-5f), 0.1f);

    int lrow = tid >> 2, lk = (tid & 3) * 4;

    // stage Q transposed, folding scale^2 = 1/8
    {
        const float* Qp = Qh + ((size_t)bh * SEQ + q0) * HD;
#pragma unroll
        for (int u = 0; u < 4; ++u) {
            int dd = lk + u * 16;
            float4 v = *(const float4*)(Qp + (size_t)lrow * HD + dd);
            Qt[dd + 0][lrow] = v.x * 0.125f;
            Qt[dd + 1][lrow] = v.y * 0.125f;
            Qt[dd + 2][lrow] = v.z * 0.125f;
            Qt[dd + 3][lrow] = v.w * 0.125f;
        }
    }

    // stream zeros to the fully-masked qk region (k-tiles qt+1..31)
    {
        float4 z4 = make_float4(0.f, 0.f, 0.f, 0.f);
        size_t rowbase = ((size_t)bh * SEQ + q0) * SEQ;
        for (int t = qt + 1; t < NT; ++t) {
            float* p = qkout + rowbase + (size_t)lrow * SEQ + t * 64 + (tid & 3) * 16;
#pragma unroll
            for (int u = 0; u < 4; ++u) *(float4*)(p + u * 4) = z4;
        }
    }

    float m[4], l[4], O[4][4];
#pragma unroll
    for (int i = 0; i < 4; ++i) {
        m[i] = 0.f; l[i] = 0.f;   // m=0 is always a valid shift: masked zeros exist
#pragma unroll
        for (int j = 0; j < 4; ++j) O[i][j] = 0.f;
    }

    const float* Kp = Kh + (size_t)bh * SEQ * HD;
    const float* Vp = Vh + (size_t)bh * SEQ * HD;

    for (int t = 0; t <= qt; ++t) {
        int k0 = t * 64;
        __syncthreads();  // previous PV (reads of KP/Vs) done
#pragma unroll
        for (int u = 0; u < 4; ++u) {
            int dd = lk + u * 16;
            float4 kv = *(const float4*)(Kp + (size_t)(k0 + lrow) * HD + dd);
            KP[dd + 0][lrow] = kv.x; KP[dd + 1][lrow] = kv.y;
            KP[dd + 2][lrow] = kv.z; KP[dd + 3][lrow] = kv.w;
            float4 vv = *(const float4*)(Vp + (size_t)(k0 + lrow) * HD + dd);
            *(float4*)&Vs[lrow][dd] = vv;
        }
        __syncthreads();

        float zfc[4];
#pragma unroll
        for (int j = 0; j < 4; ++j)
            zfc[j] = (KP[0][tx * 4 + j] == 0.0f) ? zf : 1.0f;

        float sc[4][4] = {};
#pragma unroll 8
        for (int kk = 0; kk < 64; ++kk) {
            float4 a4 = *(const float4*)&Qt[kk][ty * 4];
            float4 b4 = *(const float4*)&KP[kk][tx * 4];
            float aa[4] = {a4.x, a4.y, a4.z, a4.w};
            float bb[4] = {b4.x, b4.y, b4.z, b4.w};
#pragma unroll
            for (int i = 0; i < 4; ++i)
#pragma unroll
                for (int j = 0; j < 4; ++j)
                    sc[i][j] = fmaf(aa[i], bb[j], sc[i][j]);
        }

        size_t qkbase = ((size_t)bh * SEQ + q0) * SEQ + k0;
#pragma unroll
        for (int i = 0; i < 4; ++i) {
            int qr = q0 + ty * 4 + i;
#pragma unroll
            for (int j = 0; j < 4; ++j) {
                int kc = k0 + tx * 4 + j;
                sc[i][j] = (kc > qr) ? 0.0f : sc[i][j] * zfc[j];
            }
            float4 o = {sc[i][0], sc[i][1], sc[i][2], sc[i][3]};
            *(float4*)(qkout + qkbase + (size_t)(ty * 4 + i) * SEQ + tx * 4) = o;

            // online softmax update across the 16 tx lanes of this row
            float mt = fmaxf(fmaxf(sc[i][0], sc[i][1]), fmaxf(sc[i][2], sc[i][3]));
#pragma unroll
            for (int off = 1; off < 16; off <<= 1)
                mt = fmaxf(mt, __shfl_xor(mt, off));
            float mn = fmaxf(m[i], mt);
            float alpha = __expf(m[i] - mn);
            float ps = 0.f;
#pragma unroll
            for (int j = 0; j < 4; ++j) {
                sc[i][j] = __expf(sc[i][j] - mn);
                ps += sc[i][j];
            }
#pragma unroll
            for (int off = 1; off < 16; off <<= 1)
                ps += __shfl_xor(ps, off);
            l[i] = l[i] * alpha + ps;
            m[i] = mn;
#pragma unroll
            for (int j = 0; j < 4; ++j) O[i][j] *= alpha;
        }

        __syncthreads();  // all reads of KP-as-K done; reuse as P^T
#pragma unroll
        for (int i = 0; i < 4; ++i)
#pragma unroll
            for (int j = 0; j < 4; ++j)
                KP[tx * 4 + j][ty * 4 + i] = sc[i][j];
        __syncthreads();

#pragma unroll 8
        for (int c = 0; c < 64; ++c) {
            float4 p4 = *(const float4*)&KP[c][ty * 4];
            float4 v4 = *(const float4*)&Vs[c][tx * 4];
            float pp[4] = {p4.x, p4.y, p4.z, p4.w};
            float vv[4] = {v4.x, v4.y, v4.z, v4.w};
#pragma unroll
            for (int i = 0; i < 4; ++i)
#pragma unroll
                for (int j = 0; j < 4; ++j)
                    O[i][j] = fmaf(pp[i], vv[j], O[i][j]);
        }
    }

    // masked remainder: (31-qt) tiles of zeros -> weight e^{-m} each
    {
        int rem = NT - 1 - qt;
        const float* sufp = suf + ((size_t)bh * (NT + 1) + qt + 1) * HD + tx * 4;
        float4 sv = *(const float4*)sufp;
        float svv[4] = {sv.x, sv.y, sv.z, sv.w};
#pragma unroll
        for (int i = 0; i < 4; ++i) {
            float e = __expf(-m[i]);
            l[i] += (float)(64 * rem) * e;
#pragma unroll
            for (int j = 0; j < 4; ++j)
                O[i][j] = fmaf(e, svv[j], O[i][j]);
        }
    }

    // normalize + write attn in (B,S,D) layout for the output GEMM
#pragma unroll
    for (int i = 0; i < 4; ++i) {
        float inv = 1.0f / l[i];
        int s = q0 + ty * 4 + i;
        float4 o = {O[i][0] * inv, O[i][1] * inv, O[i][2] * inv, O[i][3] * inv};
        *(float4*)(AT + ((size_t)b * SEQ + s) * DIM + h * HD + tx * 4) = o;
    }
}

// ---------------- launch ----------------
extern "C" void kernel_launch(void* const* d_in, const int* in_sizes, int n_in,
                              void* d_out, int out_size, void* d_ws, size_t ws_size,
                              hipStream_t stream)
{
    const float* x   = (const float*)d_in[0];
    const float* Wq  = (const float*)d_in[1];
    const float* bq  = (const float*)d_in[2];
    const float* Wk  = (const float*)d_in[3];
    const float* Wv  = (const float*)d_in[4];
    const float* bv  = (const float*)d_in[5];
    const float* Wo  = (const float*)d_in[6];
    const float* bo  = (const float*)d_in[7];
    const float* fac = (const float*)d_in[8];

    float* out = (float*)d_out;           // (B,S,D)
    float* qk  = out + 4194304;           // (B,H,S,S)

    float* ws   = (float*)d_ws;           // needs ~68.2 MB
    float* Qh   = ws;                     // (B,H,S,hd)
    float* Kh   = Qh + 4194304;
    float* Vh   = Kh + 4194304;
    float* AT   = Vh + 4194304;           // attn in (B,S,D)
    float* cosT = AT + 4194304;
    float* sinT = cosT + 65536;
    float* suf  = sinT + 65536;           // (B*H, 33, 64)

    rope_tables_k<<<256, 256, 0, stream>>>(cosT, sinT);
    gemm_nt_k<<<dim3(16, 64, 3), 256, 0, stream>>>(x, AT, Wq, bq, Wk, Wv, bv, Wo, bo,
                                                   cosT, sinT, Qh, Kh, Vh, out, 0);
    vsuffix_k<<<32, 256, 0, stream>>>(Vh, suf);
    attn_k<<<dim3(32, 32), 256, 0, stream>>>(Qh, Kh, Vh, suf, fac, qk, AT);
    gemm_nt_k<<<dim3(16, 64, 1), 256, 0, stream>>>(x, AT, Wq, bq, Wk, Wv, bv, Wo, bo,
                                                   cosT, sinT, Qh, Kh, Vh, out, 3);
}